// Round 4
// baseline (289.429 us; speedup 1.0000x reference)
//
#include <hip/hip_runtime.h>

#define BINS 10
#define NTHR 9   // thresholds j=1..9: bin >= j  <=>  y >= (float)j

// Per-element: y = |x-t|*9.9999 (one rounding, same as ref), BCE partial in
// log2 domain. Sums: cumulative-threshold cndmask+add. Counts: ballot ->
// s_bcnt1 on the SCALAR pipe (v_cmp result shared with the cndmask).
// GUARD variant keeps all lanes active (no divergence): dead lanes get
// y=-1 (fails all thresholds) and s=0.
template<bool GUARD>
__device__ __forceinline__ void accum_elem(float xx, float tt, bool live,
                                           float* __restrict__ S,
                                           unsigned* __restrict__ wcnt,
                                           float& s_total)
{
    float y = fabsf(xx - tt) * 9.9999f;
    float l1 = __log2f(xx);
    float l2 = __log2f(1.0f - xx);
    float s = __builtin_fmaf(tt, l1 - l2, l2);   // t*log2(x)+(1-t)*log2(1-x)
    if (GUARD) {
        y = live ? y : -1.0f;
        s = live ? s : 0.0f;
    }
    s_total += s;
#pragma unroll
    for (int j = 0; j < NTHR; ++j) {
        bool p = (y >= (float)(j + 1));
        S[j] += p ? s : 0.0f;                            // cndmask + add (VALU)
        wcnt[j] += (unsigned)__popcll(__ballot(p));      // s_bcnt1 + s_add (SALU)
    }
}

template<bool GUARD>
__device__ __forceinline__ void accum4(float4 xv, float4 tv, bool live,
                                       float* __restrict__ S,
                                       unsigned* __restrict__ wcnt, float& st)
{
    accum_elem<GUARD>(xv.x, tv.x, live, S, wcnt, st);
    accum_elem<GUARD>(xv.y, tv.y, live, S, wcnt, st);
    accum_elem<GUARD>(xv.z, tv.z, live, S, wcnt, st);
    accum_elem<GUARD>(xv.w, tv.w, live, S, wcnt, st);
}

// 4 waves/EU floor -> compiler may use up to 128 VGPRs: prefetch buffers
// stay live across compute instead of forcing vmcnt(0) right after issue.
__global__ __launch_bounds__(256, 4) void ghm_partial(
    const float* __restrict__ x, const float* __restrict__ t,
    float* __restrict__ psum, unsigned* __restrict__ pcnt,
    int n4, long long n_total, int nblocks)
{
    float S[NTHR];
    unsigned wcnt[NTHR];
    float s_total = 0.0f;
#pragma unroll
    for (int j = 0; j < NTHR; ++j) { S[j] = 0.0f; wcnt[j] = 0u; }

    const float4* __restrict__ x4 = (const float4*)x;
    const float4* __restrict__ t4 = (const float4*)t;
    const int tid = blockIdx.x * blockDim.x + threadIdx.x;
    const int stride = gridDim.x * blockDim.x;        // pair stride
    const int iters = n4 / (2 * stride);              // uniform trip count

    // Main pipelined loop: 2 pairs (8 elems, 64 B) per iteration, next
    // iteration's 2 pairs prefetched while current computes.
    if (iters > 0) {
        long long i = tid;
        float4 ax = x4[i],          at_ = t4[i];
        float4 bx = x4[i + stride], bt  = t4[i + stride];
        for (int k = 0; ; ++k) {
            bool more = (k + 1 < iters);
            long long nx = i + 2LL * stride;
            float4 cx, ct, dx, dt;
            if (more) {
                cx = x4[nx];          ct = t4[nx];
                dx = x4[nx + stride]; dt = t4[nx + stride];
            }
            accum4<false>(ax, at_, true, S, wcnt, s_total);
            accum4<false>(bx, bt,  true, S, wcnt, s_total);
            if (!more) break;
            ax = cx; at_ = ct; bx = dx; bt = dt; i = nx;
        }
    }

    // Remainder pairs: < 2*stride pairs remain -> at most 2 guarded
    // pair-iterations per thread. Uniform block-level skip; inside, all
    // lanes stay active (live-flag instead of branch).
    long long r0 = (long long)tid + (long long)iters * 2LL * stride;
    long long blk_min = (long long)blockIdx.x * blockDim.x + (long long)iters * 2LL * stride;
    if (blk_min < n4) {
#pragma unroll
        for (int q = 0; q < 2; ++q) {
            long long r = r0 + (long long)q * stride;
            bool live = r < n4;
            int ri = live ? (int)r : 0;
            float4 xv = x4[ri], tv = t4[ri];
            accum4<true>(xv, tv, live, S, wcnt, s_total);
        }
    }

    // Scalar tail (N % 4 elements): block 0 only, guarded, no divergence.
    long long tail_base = (long long)n4 * 4;
    if (blockIdx.x == 0 && tail_base < n_total) {
        long long e = tail_base + threadIdx.x;
        bool live = e < n_total;
        long long ei = live ? e : (n_total - 1);
        accum_elem<true>(x[ei], t[ei], live, S, wcnt, s_total);
    }

    // Wave reduction: only the float sums need shuffles (counts are already
    // wave-level scalars from the ballots).
#pragma unroll
    for (int off = 32; off > 0; off >>= 1) s_total += __shfl_down(s_total, off, 64);
#pragma unroll
    for (int j = 0; j < NTHR; ++j) {
#pragma unroll
        for (int off = 32; off > 0; off >>= 1) S[j] += __shfl_down(S[j], off, 64);
    }

    __shared__ float s_sum[4][NTHR + 1];
    __shared__ unsigned s_cnt[4][NTHR];
    int lane = threadIdx.x & 63;
    int wv = threadIdx.x >> 6;
    if (lane == 0) {
        s_sum[wv][0] = s_total;
#pragma unroll
        for (int j = 0; j < NTHR; ++j) { s_sum[wv][j + 1] = S[j]; s_cnt[wv][j] = wcnt[j]; }
    }
    __syncthreads();
    // psum rows: 0 = S_total, 1..9 = cumulative Sc_j ; pcnt rows 0..8 = C_j
    if (threadIdx.x < NTHR + 1) {
        int r = threadIdx.x;
        float s = 0.0f;
#pragma unroll
        for (int w = 0; w < 4; ++w) s += s_sum[w][r];
        psum[(size_t)r * nblocks + blockIdx.x] = s;
        if (r < NTHR) {
            unsigned c = 0u;
#pragma unroll
            for (int w = 0; w < 4; ++w) c += s_cnt[w][r];
            pcnt[(size_t)r * nblocks + blockIdx.x] = c;
        }
    }
}

// Single block: coalesced bin-major reduction, difference cumulative -> bins,
// beta, weighted total.
__global__ __launch_bounds__(256) void ghm_final(
    const float* __restrict__ psum, const unsigned* __restrict__ pcnt,
    float* __restrict__ out, int nblocks, float Nf, long long N)
{
    float rs[NTHR + 1];
    unsigned rc[NTHR];
#pragma unroll
    for (int r = 0; r < NTHR + 1; ++r) rs[r] = 0.0f;
#pragma unroll
    for (int r = 0; r < NTHR; ++r) rc[r] = 0u;

    for (int i = threadIdx.x; i < nblocks; i += 256) {
#pragma unroll
        for (int r = 0; r < NTHR + 1; ++r) rs[r] += psum[(size_t)r * nblocks + i];
#pragma unroll
        for (int r = 0; r < NTHR; ++r) rc[r] += pcnt[(size_t)r * nblocks + i];
    }

#pragma unroll
    for (int r = 0; r < NTHR + 1; ++r) {
#pragma unroll
        for (int off = 32; off > 0; off >>= 1) rs[r] += __shfl_down(rs[r], off, 64);
    }
#pragma unroll
    for (int r = 0; r < NTHR; ++r) {
#pragma unroll
        for (int off = 32; off > 0; off >>= 1) rc[r] += (unsigned)__shfl_down((int)rc[r], off, 64);
    }

    __shared__ float s_sum[4][NTHR + 1];
    __shared__ unsigned s_cnt[4][NTHR];
    int lane = threadIdx.x & 63;
    int wv = threadIdx.x >> 6;
    if (lane == 0) {
#pragma unroll
        for (int r = 0; r < NTHR + 1; ++r) s_sum[wv][r] = rs[r];
#pragma unroll
        for (int r = 0; r < NTHR; ++r) s_cnt[wv][r] = rc[r];
    }
    __syncthreads();

    if (threadIdx.x == 0) {
        float Sc[BINS + 1];      // cumulative sums: Sc[0]=total, Sc[10]=0
        float Cc[BINS + 1];      // cumulative counts: Cc[0]=N, Cc[10]=0
#pragma unroll
        for (int r = 0; r < NTHR + 1; ++r) {
            float s = 0.0f;
#pragma unroll
            for (int w = 0; w < 4; ++w) s += s_sum[w][r];
            Sc[r] = s;
        }
        Sc[BINS] = 0.0f;
        Cc[0] = (float)N;
#pragma unroll
        for (int r = 0; r < NTHR; ++r) {
            unsigned c = 0u;
#pragma unroll
            for (int w = 0; w < 4; ++w) c += s_cnt[w][r];
            Cc[r + 1] = (float)c;
        }
        Cc[BINS] = 0.0f;

        float nonempty = 0.0f;
        float cnt[BINS], sb[BINS];
#pragma unroll
        for (int b = 0; b < BINS; ++b) {
            cnt[b] = Cc[b] - Cc[b + 1];
            sb[b] = Sc[b] - Sc[b + 1];
            nonempty += (cnt[b] > 0.0f) ? 1.0f : 0.0f;
        }
        float total = 0.0f;
#pragma unroll
        for (int b = 0; b < BINS; ++b) {
            float gd = cnt[b] * nonempty;
            gd = gd < 1.0f ? 1.0f : gd;      // clip(gd, 1, None)
            total += sb[b] * (Nf / gd);      // beta = N/gd
        }
        const float LN2 = 0.69314718055994530942f;
        out[0] = -LN2 * total / Nf;          // undo log2 scale + negation, mean
    }
}

extern "C" void kernel_launch(void* const* d_in, const int* in_sizes, int n_in,
                              void* d_out, int out_size, void* d_ws, size_t ws_size,
                              hipStream_t stream) {
    const float* x = (const float*)d_in[0];
    const float* t = (const float*)d_in[1];
    float* out = (float*)d_out;

    long long N = (long long)in_sizes[0];
    int n4 = (int)(N / 4);

    int nblocks = 2048;   // 8192 waves; resident 16/CU (launch_bounds 256,4)
    size_t per_block = (size_t)(NTHR + 1) * sizeof(float) + (size_t)NTHR * sizeof(unsigned);
    size_t maxb = ws_size / per_block;
    if ((size_t)nblocks > maxb) nblocks = (int)maxb;
    if (nblocks < 1) nblocks = 1;

    float* psum = (float*)d_ws;                                         // [10][nblocks]
    unsigned* pcnt = (unsigned*)(psum + (size_t)(NTHR + 1) * nblocks);  // [9][nblocks]

    ghm_partial<<<nblocks, 256, 0, stream>>>(x, t, psum, pcnt, n4, N, nblocks);
    ghm_final<<<1, 256, 0, stream>>>(psum, pcnt, out, nblocks, (float)N, N);
}

// Round 5
// 285.635 us; speedup vs baseline: 1.0133x; 1.0133x over previous
//
#include <hip/hip_runtime.h>

#define BINS 10
#define NTHR 9      // thresholds j=1..9: bin >= j  <=>  y >= (float)j
#define TPB 256
#define F4PT 2      // float4 per thread per array per iteration
#define TILE_F4 (TPB * F4PT)   // 512 float4 = 8 KB per array per buffer

// Async 16B global -> LDS (no destination VGPR: compiler cannot serialize on
// register reuse). lds dest must be wave-uniform; HW scatters lane*16.
__device__ __forceinline__ void stage16(const float4* g, float4* l) {
    __builtin_amdgcn_global_load_lds(
        (const __attribute__((address_space(1))) unsigned int*)g,
        (__attribute__((address_space(3))) unsigned int*)l,
        16, 0, 0);
}

// Per-element accumulation (unchanged from r4, absmax=0-verified):
// sums via cumulative-threshold cndmask+add, counts via ballot->SALU popcount.
template<bool GUARD>
__device__ __forceinline__ void accum_elem(float xx, float tt, bool live,
                                           float* __restrict__ S,
                                           unsigned* __restrict__ wcnt,
                                           float& s_total)
{
    float y = fabsf(xx - tt) * 9.9999f;
    float l1 = __log2f(xx);
    float l2 = __log2f(1.0f - xx);
    float s = __builtin_fmaf(tt, l1 - l2, l2);   // t*log2(x)+(1-t)*log2(1-x)
    if (GUARD) {
        y = live ? y : -1.0f;
        s = live ? s : 0.0f;
    }
    s_total += s;
#pragma unroll
    for (int j = 0; j < NTHR; ++j) {
        bool p = (y >= (float)(j + 1));
        S[j] += p ? s : 0.0f;
        wcnt[j] += (unsigned)__popcll(__ballot(p));
    }
}

template<bool GUARD>
__device__ __forceinline__ void accum4(float4 xv, float4 tv, bool live,
                                       float* __restrict__ S,
                                       unsigned* __restrict__ wcnt, float& st)
{
    accum_elem<GUARD>(xv.x, tv.x, live, S, wcnt, st);
    accum_elem<GUARD>(xv.y, tv.y, live, S, wcnt, st);
    accum_elem<GUARD>(xv.z, tv.z, live, S, wcnt, st);
    accum_elem<GUARD>(xv.w, tv.w, live, S, wcnt, st);
}

__global__ __launch_bounds__(TPB) void ghm_partial(
    const float* __restrict__ x, const float* __restrict__ t,
    float* __restrict__ psum, unsigned* __restrict__ pcnt,
    int n4, long long n_total, int nblocks)
{
    // 2 arrays x 2 buffers x 8 KB = 32 KB -> 5 blocks/CU, 20 waves/CU
    __shared__ float4 sx[2][TILE_F4];
    __shared__ float4 st_[2][TILE_F4];

    float S[NTHR];
    unsigned wcnt[NTHR];
    float s_total = 0.0f;
#pragma unroll
    for (int j = 0; j < NTHR; ++j) { S[j] = 0.0f; wcnt[j] = 0u; }

    const float4* __restrict__ x4 = (const float4*)x;
    const float4* __restrict__ t4 = (const float4*)t;
    const int tid = threadIdx.x;
    const int wv = tid >> 6;            // wave id in block
    const int wbase = wv * 64;          // wave's 64-slot section
    const long long iter_stride = (long long)nblocks * TILE_F4;  // f4 per iter, whole grid
    const int iters = (int)((long long)n4 / iter_stride);

    if (iters > 0) {
        // stage tile 0 into buffer 0
        {
            long long gb = (long long)blockIdx.x * TILE_F4;
#pragma unroll
            for (int j = 0; j < F4PT; ++j) {
                // global: lane-contiguous 16B; lds: wave-uniform base (+lane*16 by HW)
                stage16(&x4[gb + j * TPB + tid], &sx[0][j * TPB + wbase]);
                stage16(&t4[gb + j * TPB + tid], &st_[0][j * TPB + wbase]);
            }
        }
        __syncthreads();   // drains vmcnt -> tile 0 resident

        for (int k = 0; ; ++k) {
            int cur = k & 1;
            if (k + 1 < iters) {
                long long gb = (long long)(k + 1) * iter_stride + (long long)blockIdx.x * TILE_F4;
                int nxt = cur ^ 1;
#pragma unroll
                for (int j = 0; j < F4PT; ++j) {
                    stage16(&x4[gb + j * TPB + tid], &sx[nxt][j * TPB + wbase]);
                    stage16(&t4[gb + j * TPB + tid], &st_[nxt][j * TPB + wbase]);
                }
            }
            // compute current tile from LDS (ds_read_b128, lane-contiguous)
#pragma unroll
            for (int j = 0; j < F4PT; ++j) {
                float4 xv = sx[cur][j * TPB + tid];
                float4 tv = st_[cur][j * TPB + tid];
                accum4<false>(xv, tv, true, S, wcnt, s_total);
            }
            if (k + 1 >= iters) break;
            __syncthreads();  // waits staged tile k+1 (vmcnt) + protects buffer reuse
        }
    }

    // Remainder float4s (< iter_stride of them): guarded plain loads, no divergence.
    long long done = (long long)iters * iter_stride;
    if (done < n4) {
        long long gtid = (long long)blockIdx.x * TPB + tid;
        long long total_thr = (long long)nblocks * TPB;
#pragma unroll
        for (int q = 0; q < F4PT; ++q) {
            long long r = done + gtid + (long long)q * total_thr;
            bool live = r < n4;
            long long ri = live ? r : 0;
            float4 xv = x4[ri], tv = t4[ri];
            accum4<true>(xv, tv, live, S, wcnt, s_total);
        }
    }

    // Scalar tail (N % 4): block 0, guarded.
    long long tail_base = (long long)n4 * 4;
    if (blockIdx.x == 0 && tail_base < n_total) {
        long long e = tail_base + tid;
        bool live = e < n_total;
        long long ei = live ? e : (n_total - 1);
        accum_elem<true>(x[ei], t[ei], live, S, wcnt, s_total);
    }

    // Wave reduction: floats only (counts already wave-scalars via ballot).
#pragma unroll
    for (int off = 32; off > 0; off >>= 1) s_total += __shfl_down(s_total, off, 64);
#pragma unroll
    for (int j = 0; j < NTHR; ++j) {
#pragma unroll
        for (int off = 32; off > 0; off >>= 1) S[j] += __shfl_down(S[j], off, 64);
    }

    __shared__ float red_s[4][NTHR + 1];
    __shared__ unsigned red_c[4][NTHR];
    int lane = tid & 63;
    __syncthreads();   // LDS buffers reuse-safe vs red_* aliasing? separate arrays; barrier for epilogue ordering
    if (lane == 0) {
        red_s[wv][0] = s_total;
#pragma unroll
        for (int j = 0; j < NTHR; ++j) { red_s[wv][j + 1] = S[j]; red_c[wv][j] = wcnt[j]; }
    }
    __syncthreads();
    // psum rows: 0 = S_total, 1..9 = cumulative Sc_j ; pcnt rows 0..8 = C_j
    if (tid < NTHR + 1) {
        int r = tid;
        float s = 0.0f;
#pragma unroll
        for (int w = 0; w < 4; ++w) s += red_s[w][r];
        psum[(size_t)r * nblocks + blockIdx.x] = s;
        if (r < NTHR) {
            unsigned c = 0u;
#pragma unroll
            for (int w = 0; w < 4; ++w) c += red_c[w][r];
            pcnt[(size_t)r * nblocks + blockIdx.x] = c;
        }
    }
}

// Single block: coalesced bin-major reduction, difference cumulative -> bins,
// beta, weighted total.
__global__ __launch_bounds__(256) void ghm_final(
    const float* __restrict__ psum, const unsigned* __restrict__ pcnt,
    float* __restrict__ out, int nblocks, float Nf, long long N)
{
    float rs[NTHR + 1];
    unsigned rc[NTHR];
#pragma unroll
    for (int r = 0; r < NTHR + 1; ++r) rs[r] = 0.0f;
#pragma unroll
    for (int r = 0; r < NTHR; ++r) rc[r] = 0u;

    for (int i = threadIdx.x; i < nblocks; i += 256) {
#pragma unroll
        for (int r = 0; r < NTHR + 1; ++r) rs[r] += psum[(size_t)r * nblocks + i];
#pragma unroll
        for (int r = 0; r < NTHR; ++r) rc[r] += pcnt[(size_t)r * nblocks + i];
    }

#pragma unroll
    for (int r = 0; r < NTHR + 1; ++r) {
#pragma unroll
        for (int off = 32; off > 0; off >>= 1) rs[r] += __shfl_down(rs[r], off, 64);
    }
#pragma unroll
    for (int r = 0; r < NTHR; ++r) {
#pragma unroll
        for (int off = 32; off > 0; off >>= 1) rc[r] += (unsigned)__shfl_down((int)rc[r], off, 64);
    }

    __shared__ float s_sum[4][NTHR + 1];
    __shared__ unsigned s_cnt[4][NTHR];
    int lane = threadIdx.x & 63;
    int wv = threadIdx.x >> 6;
    if (lane == 0) {
#pragma unroll
        for (int r = 0; r < NTHR + 1; ++r) s_sum[wv][r] = rs[r];
#pragma unroll
        for (int r = 0; r < NTHR; ++r) s_cnt[wv][r] = rc[r];
    }
    __syncthreads();

    if (threadIdx.x == 0) {
        float Sc[BINS + 1];      // cumulative sums: Sc[0]=total, Sc[10]=0
        float Cc[BINS + 1];      // cumulative counts: Cc[0]=N, Cc[10]=0
#pragma unroll
        for (int r = 0; r < NTHR + 1; ++r) {
            float s = 0.0f;
#pragma unroll
            for (int w = 0; w < 4; ++w) s += s_sum[w][r];
            Sc[r] = s;
        }
        Sc[BINS] = 0.0f;
        Cc[0] = (float)N;
#pragma unroll
        for (int r = 0; r < NTHR; ++r) {
            unsigned c = 0u;
#pragma unroll
            for (int w = 0; w < 4; ++w) c += s_cnt[w][r];
            Cc[r + 1] = (float)c;
        }
        Cc[BINS] = 0.0f;

        float nonempty = 0.0f;
        float cnt[BINS], sb[BINS];
#pragma unroll
        for (int b = 0; b < BINS; ++b) {
            cnt[b] = Cc[b] - Cc[b + 1];
            sb[b] = Sc[b] - Sc[b + 1];
            nonempty += (cnt[b] > 0.0f) ? 1.0f : 0.0f;
        }
        float total = 0.0f;
#pragma unroll
        for (int b = 0; b < BINS; ++b) {
            float gd = cnt[b] * nonempty;
            gd = gd < 1.0f ? 1.0f : gd;      // clip(gd, 1, None)
            total += sb[b] * (Nf / gd);      // beta = N/gd
        }
        const float LN2 = 0.69314718055994530942f;
        out[0] = -LN2 * total / Nf;          // undo log2 scale + negation, mean
    }
}

extern "C" void kernel_launch(void* const* d_in, const int* in_sizes, int n_in,
                              void* d_out, int out_size, void* d_ws, size_t ws_size,
                              hipStream_t stream) {
    const float* x = (const float*)d_in[0];
    const float* t = (const float*)d_in[1];
    float* out = (float*)d_out;

    long long N = (long long)in_sizes[0];
    int n4 = (int)(N / 4);

    int nblocks = 2048;
    size_t per_block = (size_t)(NTHR + 1) * sizeof(float) + (size_t)NTHR * sizeof(unsigned);
    size_t maxb = ws_size / per_block;
    if ((size_t)nblocks > maxb) nblocks = (int)maxb;
    if (nblocks < 1) nblocks = 1;

    float* psum = (float*)d_ws;                                         // [10][nblocks]
    unsigned* pcnt = (unsigned*)(psum + (size_t)(NTHR + 1) * nblocks);  // [9][nblocks]

    ghm_partial<<<nblocks, TPB, 0, stream>>>(x, t, psum, pcnt, n4, N, nblocks);
    ghm_final<<<1, 256, 0, stream>>>(psum, pcnt, out, nblocks, (float)N, N);
}